// Round 7
// baseline (1172.803 us; speedup 1.0000x reference)
//
#include <hip/hip_runtime.h>

// ---------------- problem constants (match reference) ----------------
#define Zl      384
#define MBr     46
#define NBc     68
#define DEG     7
#define K_INFO  8448
#define N_TX    25344
#define N_LDPC  (NBc * Zl)        // 26112
#define M_CHK   (MBr * Zl)        // 17664
#define E_EDGE  (MBr * DEG * Zl)  // 123648
#define BATCH   128
#define NUM_ITER 20
#define LLR_MAXF 20.0f
#define BCAP    32

// Numerics model (hypothesis X1): reference re-executed on host by XLA-CPU,
// f32 throughout, with the algebraic-simplifier rewrite
//   add(lch, scatter(zeros, col, m_cv)) -> scatter(lch, col, m_cv)
// so the VN sum accumulates LCH FIRST, then messages in ascending edge id.

// ---------------------------------------------------------------------
// prep (scalar): lch[(2Z+n)*128 + b] = -clip(llr[b*N_TX + n])
// first 2Z rows of lch are zeroed via hipMemsetAsync.
// ---------------------------------------------------------------------
__global__ void prep_s(const float* __restrict__ llr, float* __restrict__ lch) {
    int tid = blockIdx.x * 256 + threadIdx.x;
    if (tid < N_TX * BATCH) {
        int n = tid / BATCH;
        int b = tid - n * BATCH;
        float v = llr[b * N_TX + n];
        v = fminf(fmaxf(v, -LLR_MAXF), LLR_MAXF);
        lch[(2 * Zl + n) * BATCH + b] = -v;
    }
}

// ---------------------------------------------------------------------
// adjacency build: ONE thread, sequential over base edges ascending ->
// per-column slots in ascending edge id. col[be*Z] = c*Z + shift.
// ---------------------------------------------------------------------
__global__ void build1(const int* __restrict__ col,
                       int* __restrict__ bcount, int* __restrict__ badj) {
    if (blockIdx.x == 0 && threadIdx.x == 0) {
        int cnt[NBc];
        for (int c = 0; c < NBc; ++c) cnt[c] = 0;
        for (int be = 0; be < MBr * DEG; ++be) {
            const int v0 = col[be * Zl];
            const int c  = v0 / Zl;
            const int sh = v0 - c * Zl;
            if (cnt[c] < BCAP) badj[c * BCAP + cnt[c]] = (be << 16) | sh;
            cnt[c]++;
        }
        for (int c = 0; c < NBc; ++c) bcount[c] = (cnt[c] < BCAP) ? cnt[c] : BCAP;
    }
}

// ---------------------------------------------------------------------
// CN update (scalar f32): block = one check node, thread = one batch elem.
// m_vc = x[col[e]] - m_cv_old; two-min with first-argmin; sign parity.
// ---------------------------------------------------------------------
template <bool FIRST>
__global__ void cn_s(const float* __restrict__ x, float* __restrict__ mcv,
                     const int* __restrict__ col) {
    const int b  = threadIdx.x;          // 0..127
    const int cn = blockIdx.x;           // 0..M_CHK-1
    const int r  = cn / Zl;
    const int i  = cn - r * Zl;
    const int e0 = r * DEG * Zl + i;

    float min1 = 1e30f, min2 = 1e30f;
    int amin = 0;
    unsigned nm = 0u;

    for (int d = 0; d < DEG; ++d) {
        const int e = e0 + d * Zl;
        const float m  = FIRST ? 0.0f : mcv[e * BATCH + b];
        const float tv = x[col[e] * BATCH + b] - m;
        const float mag = fabsf(tv);
        if (tv < 0.0f) nm |= (1u << d);
        if (mag < min1) { min2 = min1; min1 = mag; amin = d; }
        else if (mag < min2) { min2 = mag; }
    }

    const float stot = (__popc(nm) & 1) ? -1.0f : 1.0f;

    for (int d = 0; d < DEG; ++d) {
        const int e = e0 + d * Zl;
        const float mag = (d == amin) ? min2 : min1;
        const float s   = ((nm >> d) & 1u) ? -stot : stot;
        mcv[e * BATCH + b] = s * mag;
    }
}

// ---------------------------------------------------------------------
// VN update (scalar f32, LCH-FIRST): block = variable node, thread = batch.
// x[v] = scatter-add into lch: s = lch[v]; s += m_cv[e] ascending edge id.
// ---------------------------------------------------------------------
__global__ void vn_s(const float* __restrict__ lch, const float* __restrict__ mcv,
                     const int* __restrict__ bcount, const int* __restrict__ badj,
                     float* __restrict__ x) {
    const int b = threadIdx.x;
    const int v = blockIdx.x;
    const int c = v / Zl;
    const int j = v - c * Zl;
    const int cnt = bcount[c];
    float s = lch[v * BATCH + b];        // lch FIRST (scatter init), then edges
    for (int k = 0; k < cnt; ++k) {
        const int pk = badj[c * BCAP + k];
        const int be = pk >> 16;
        const int sh = pk & 0xFFFF;
        int i = j - sh;
        if (i < 0) i += Zl;
        s += mcv[(be * Zl + i) * BATCH + b];
    }
    x[v * BATCH + b] = s;
}

// ---------------------------------------------------------------------
// output (scalar): out[b*K + k] = -x[k*128 + b]
// ---------------------------------------------------------------------
__global__ void out_s(const float* __restrict__ x, float* __restrict__ out) {
    int tid = blockIdx.x * 256 + threadIdx.x;
    if (tid < BATCH * K_INFO) {
        int b = tid / K_INFO;
        int k = tid - b * K_INFO;
        out[tid] = -x[k * BATCH + b];
    }
}

// ---------------------------------------------------------------------
extern "C" void kernel_launch(void* const* d_in, const int* in_sizes, int n_in,
                              void* d_out, int out_size, void* d_ws, size_t ws_size,
                              hipStream_t stream) {
    const float* llr = (const float*)d_in[0];
    // d_in[1] = row (unused: row index derivable from edge-id structure)
    const int* col = (const int*)d_in[2];
    float* out = (float*)d_out;

    char* ws = (char*)d_ws;
    float* lch    = (float*)ws;                                  // 13,369,344 B
    float* x      = lch + (size_t)N_LDPC * BATCH;                // 13,369,344 B
    float* mcv    = x + (size_t)N_LDPC * BATCH;                  // 63,307,776 B
    int*   bcount = (int*)(mcv + (size_t)E_EDGE * BATCH);        // 68*4
    int*   badj   = bcount + NBc;                                // 68*32*4

    hipMemsetAsync(lch, 0, (size_t)(2 * Zl) * BATCH * sizeof(float), stream);
    prep_s<<<(N_TX * BATCH) / 256, 256, 0, stream>>>(llr, lch);

    build1<<<1, 64, 0, stream>>>(col, bcount, badj);

    // iteration 1: vn_sum == lch exactly (m_cv == 0)
    cn_s<true><<<M_CHK, BATCH, 0, stream>>>(lch, mcv, col);
    vn_s<<<N_LDPC, BATCH, 0, stream>>>(lch, mcv, bcount, badj, x);

    for (int t = 1; t < NUM_ITER; ++t) {
        cn_s<false><<<M_CHK, BATCH, 0, stream>>>(x, mcv, col);
        vn_s<<<N_LDPC, BATCH, 0, stream>>>(lch, mcv, bcount, badj, x);
    }

    out_s<<<(BATCH * K_INFO + 255) / 256, 256, 0, stream>>>(x, out);
}

// Round 8
// 919.629 us; speedup vs baseline: 1.2753x; 1.2753x over previous
//
#include <hip/hip_runtime.h>

// ---------------- problem constants (match reference) ----------------
#define Zl      384
#define MBr     46
#define NBc     68
#define DEG     7
#define K_INFO  8448
#define N_TX    25344
#define N_LDPC  (NBc * Zl)        // 26112
#define M_CHK   (MBr * Zl)        // 17664
#define E_EDGE  (MBr * DEG * Zl)  // 123648
#define BATCH   128
#define NUM_ITER 20
#define LLR_MAXF 20.0f
#define BCAP    32

// NUMERICS CONTRACT (validated round 7, absmax 0.0625 vs 0.45):
//  - pure f32 end to end
//  - VN sum: accumulator starts at lch[v], then messages added in
//    ASCENDING edge-id order (XLA scatter-fusion order). Changing this
//    order produces absmax ~1.4-2.0 (measured R1-R6). DO NOT REORDER.
//  - CN: two-min with strict < (first-argmin), sign via parity mask.
// Batch elements are independent -> float4 over batch is order-safe.

// ---------------------------------------------------------------------
// prep: lch[(2Z+n)*128 + b] = -clip(llr[b*N_TX + n])   (tiled transpose)
// first 2Z rows of lch are zeroed separately via hipMemsetAsync.
// ---------------------------------------------------------------------
__global__ void prep_kernel(const float* __restrict__ llr, float* __restrict__ lch) {
    __shared__ float tile[32][33];
    const int n0 = blockIdx.x * 32, b0 = blockIdx.y * 32;
    const int tx = threadIdx.x, ty = threadIdx.y;
#pragma unroll
    for (int j = 0; j < 4; ++j) {
        int b = b0 + ty + 8 * j;
        float v = llr[b * N_TX + n0 + tx];
        v = fminf(fmaxf(v, -LLR_MAXF), LLR_MAXF);
        tile[ty + 8 * j][tx] = -v;          // [b_local][n_local]
    }
    __syncthreads();
#pragma unroll
    for (int j = 0; j < 4; ++j) {
        lch[(2 * Zl + n0 + ty + 8 * j) * BATCH + b0 + tx] = tile[tx][ty + 8 * j];
    }
}

// ---------------------------------------------------------------------
// parallel deterministic adjacency build (single block):
// slot(base-edge t) = #earlier base edges with same column  -> ascending
// base-edge id == ascending lifted edge id within each VN's list.
// col[be*Z] = c*Z + shift.
// ---------------------------------------------------------------------
__global__ void base_build_kernel(const int* __restrict__ col,
                                  int* __restrict__ bcount, int* __restrict__ badj) {
    __shared__ int sc[MBr * DEG];
    const int t = threadIdx.x;
    int c = -1, shift = 0;
    if (t < MBr * DEG) {
        const int v0 = col[t * Zl];
        c = v0 / Zl;
        shift = v0 - c * Zl;
        sc[t] = c;
    }
    if (t < NBc) bcount[t] = 0;
    __syncthreads();
    if (t < MBr * DEG) {
        int slot = 0;
        for (int u = 0; u < t; ++u) slot += (sc[u] == c) ? 1 : 0;
        if (slot < BCAP) badj[c * BCAP + slot] = (t << 16) | shift;
        atomicAdd(&bcount[c], 1);   // order-independent (count only)
    }
}

// ---------------------------------------------------------------------
// CN update: node cn = r*Z + i, edges e_d = (r*DEG+d)*Z + i.
// 32 lanes per node (float4 over batch), 8 nodes per 256-thread block.
// ---------------------------------------------------------------------
template <bool FIRST>
__global__ void cn_kernel(const float* __restrict__ x, float* __restrict__ mcv,
                          const int* __restrict__ col) {
    const int q   = threadIdx.x & 31;   // float4 index over batch
    const int sub = threadIdx.x >> 5;
    const int cn  = blockIdx.x * 8 + sub;
    const int r   = cn / Zl;
    const int i   = cn - r * Zl;
    const int ebase = r * DEG * Zl + i;

    float min1[4] = {1e30f, 1e30f, 1e30f, 1e30f};
    float min2[4] = {1e30f, 1e30f, 1e30f, 1e30f};
    int   amin[4] = {0, 0, 0, 0};
    unsigned nm[4] = {0u, 0u, 0u, 0u};

#pragma unroll
    for (int d = 0; d < DEG; ++d) {
        const int e = ebase + d * Zl;
        const int v = col[e];
        const float4 xv = ((const float4*)x)[v * 32 + q];
        float4 mc;
        if (FIRST) { mc = make_float4(0.f, 0.f, 0.f, 0.f); }
        else       { mc = ((const float4*)mcv)[e * 32 + q]; }
        const float t[4] = {xv.x - mc.x, xv.y - mc.y, xv.z - mc.z, xv.w - mc.w};
#pragma unroll
        for (int c = 0; c < 4; ++c) {
            const float mag = fabsf(t[c]);
            nm[c] |= (t[c] < 0.f ? 1u : 0u) << d;
            if (mag < min1[c]) { min2[c] = min1[c]; min1[c] = mag; amin[c] = d; }
            else if (mag < min2[c]) { min2[c] = mag; }
        }
    }

    float stot[4];
#pragma unroll
    for (int c = 0; c < 4; ++c) stot[c] = (__popc(nm[c]) & 1) ? -1.f : 1.f;

#pragma unroll
    for (int d = 0; d < DEG; ++d) {
        const int e = ebase + d * Zl;
        float o[4];
#pragma unroll
        for (int c = 0; c < 4; ++c) {
            const float m = (d == amin[c]) ? min2[c] : min1[c];
            const float s = ((nm[c] >> d) & 1u) ? -stot[c] : stot[c];
            o[c] = s * m;
        }
        ((float4*)mcv)[e * 32 + q] = make_float4(o[0], o[1], o[2], o[3]);
    }
}

// ---------------------------------------------------------------------
// VN update (LCH-FIRST): x[v] = lch[v]; then += m_cv[e], ascending e.
// 32 lanes per node (float4 over batch), 8 nodes per 256-thread block.
// ---------------------------------------------------------------------
__global__ void vn_kernel(const float* __restrict__ lch, const float* __restrict__ mcv,
                          const int* __restrict__ bcount, const int* __restrict__ badj,
                          float* __restrict__ x) {
    const int q   = threadIdx.x & 31;
    const int sub = threadIdx.x >> 5;
    const int v   = blockIdx.x * 8 + sub;
    const int c   = v / Zl;
    const int j   = v - c * Zl;
    const int cnt = min(bcount[c], BCAP);
    const int* bp = badj + c * BCAP;
    float4 s = ((const float4*)lch)[v * 32 + q];   // lch FIRST (scatter init)
    for (int k = 0; k < cnt; ++k) {
        const int pk = bp[k];
        const int be = pk >> 16;
        const int sh = pk & 0xFFFF;
        int i = j - sh;
        if (i < 0) i += Zl;
        const float4 m = ((const float4*)mcv)[(be * Zl + i) * 32 + q];
        s.x += m.x; s.y += m.y; s.z += m.z; s.w += m.w;
    }
    ((float4*)x)[v * 32 + q] = s;
}

// ---------------------------------------------------------------------
// output: out[b*K + k] = -x[k*128 + b], k < K_INFO   (tiled transpose)
// ---------------------------------------------------------------------
__global__ void out_kernel(const float* __restrict__ x, float* __restrict__ out) {
    __shared__ float tile[32][33];
    const int k0 = blockIdx.x * 32, b0 = blockIdx.y * 32;
    const int tx = threadIdx.x, ty = threadIdx.y;
#pragma unroll
    for (int j = 0; j < 4; ++j) {
        tile[ty + 8 * j][tx] = -x[(k0 + ty + 8 * j) * BATCH + b0 + tx];
    }
    __syncthreads();
#pragma unroll
    for (int j = 0; j < 4; ++j) {
        out[(b0 + ty + 8 * j) * K_INFO + k0 + tx] = tile[tx][ty + 8 * j];
    }
}

// ---------------------------------------------------------------------
extern "C" void kernel_launch(void* const* d_in, const int* in_sizes, int n_in,
                              void* d_out, int out_size, void* d_ws, size_t ws_size,
                              hipStream_t stream) {
    const float* llr = (const float*)d_in[0];
    // d_in[1] = row (unused: row index derivable from edge-id structure)
    const int* col = (const int*)d_in[2];
    float* out = (float*)d_out;

    char* ws = (char*)d_ws;
    float* lch    = (float*)ws;                                  // 13,369,344 B
    float* x      = lch + (size_t)N_LDPC * BATCH;                // 13,369,344 B
    float* mcv    = x + (size_t)N_LDPC * BATCH;                  // 63,307,776 B
    int*   bcount = (int*)(mcv + (size_t)E_EDGE * BATCH);        // 68*4
    int*   badj   = bcount + NBc;                                // 68*32*4

    hipMemsetAsync(lch, 0, (size_t)(2 * Zl) * BATCH * sizeof(float), stream);
    prep_kernel<<<dim3(N_TX / 32, BATCH / 32), dim3(32, 8), 0, stream>>>(llr, lch);

    base_build_kernel<<<1, 512, 0, stream>>>(col, bcount, badj);

    // iteration 1: vn_sum == lch exactly (m_cv == 0)
    cn_kernel<true><<<M_CHK / 8, 256, 0, stream>>>(lch, mcv, col);
    vn_kernel<<<N_LDPC / 8, 256, 0, stream>>>(lch, mcv, bcount, badj, x);

    for (int t = 1; t < NUM_ITER; ++t) {
        cn_kernel<false><<<M_CHK / 8, 256, 0, stream>>>(x, mcv, col);
        vn_kernel<<<N_LDPC / 8, 256, 0, stream>>>(lch, mcv, bcount, badj, x);
    }

    out_kernel<<<dim3(K_INFO / 32, BATCH / 32), dim3(32, 8), 0, stream>>>(x, out);
}